// Round 11
// baseline (262.947 us; speedup 1.0000x reference)
//
#include <hip/hip_runtime.h>
#include <float.h>
#include <math.h>

// Problem constants
#define TT 4096          // tokens = B*S
#define HH 1024          // hidden
#define II 512           // expert ffn hidden
#define E_R 32
#define E_T 40
#define TOPK 6
#define SCALE_F 2.5f
#define MAXTILES 224     // >= sum_e ceil(cnt_e/128); (24576+32*127)/128 = 223.75
#define NGUP (32*1024*1024)   // routed gate_up elems (first 32 experts)
#define NDWN (32*1024*512)    // down elems

typedef __bf16 bf16x8 __attribute__((ext_vector_type(8)));
typedef float f32x4 __attribute__((ext_vector_type(4)));

__device__ inline unsigned short f2bf(float f) {
  __bf16 h = (__bf16)f;
  return __builtin_bit_cast(unsigned short, h);
}

__device__ inline bf16x8 cvt8v(float4 a, float4 b) {
  bf16x8 v;
  v[0] = (__bf16)a.x; v[1] = (__bf16)a.y; v[2] = (__bf16)a.z; v[3] = (__bf16)a.w;
  v[4] = (__bf16)b.x; v[5] = (__bf16)b.y; v[6] = (__bf16)b.z; v[7] = (__bf16)b.w;
  return v;
}

// async global->LDS, 16B per lane, wave-uniform LDS base (linear dest)
__device__ inline void gload_lds16(const void* g, void* l) {
  __builtin_amdgcn_global_load_lds(
      (__attribute__((address_space(1))) void*)g,
      (__attribute__((address_space(3))) void*)l, 16, 0, 0);
}

// bf16 LDS tile: [rows][64 bf16], row stride 128B, XOR swizzle byte^=((row&7)<<4);
// staged via gload_lds with pre-swizzled SOURCE chunk, read with same XOR.
__device__ inline bf16x8 lds_frag(const unsigned short* base, int row, int kb) {
  int byte = (row * 128 + kb * 2) ^ ((row & 7) << 4);
  uint4 v = *reinterpret_cast<const uint4*>(reinterpret_cast<const char*>(base) + byte);
  return __builtin_bit_cast(bf16x8, v);
}

__device__ inline f32x4 mfma16(bf16x8 a, bf16x8 b, f32x4 c) {
  return __builtin_amdgcn_mfma_f32_16x16x32_bf16(a, b, c, 0, 0, 0);
}

// ---------------- kernel 0: one-shot weight fp32 -> bf16 (routed gup + dwn) ----------
__global__ __launch_bounds__(256) void k_convert_w(const float* __restrict__ gup,
                                                   const float* __restrict__ dwn,
                                                   uint4* __restrict__ wb) {
  unsigned i = blockIdx.x * 256 + threadIdx.x;     // one uint4 (8 bf16) per thread
  const unsigned NGq = NGUP / 8;
  const float4* src = (i < NGq)
      ? reinterpret_cast<const float4*>(gup) + (size_t)i * 2
      : reinterpret_cast<const float4*>(dwn) + (size_t)(i - NGq) * 2;
  float4 a = src[0], b = src[1];
  wb[i] = __builtin_bit_cast(uint4, cvt8v(a, b));
}

// ---------------- kernel 2a: router logits (fp32 GEMV) + fused x->bf16 convert ----------
__global__ __launch_bounds__(256) void k_logits(const float* __restrict__ x,
                                                const float* __restrict__ wcls,
                                                float* __restrict__ logits,
                                                unsigned short* __restrict__ xb) {
  __shared__ float4 ws4[E_T * 64];                 // 40 KB
  const int tid = threadIdx.x;
  const int lane = tid & 63;
  const int wave = tid >> 6;
  const int token = blockIdx.x * 4 + wave;
  const float4* x4 = reinterpret_cast<const float4*>(x);
  const float4* w4 = reinterpret_cast<const float4*>(wcls);

  float acc[E_T];
  #pragma unroll
  for (int e = 0; e < E_T; ++e) acc[e] = 0.f;

  for (int c = 0; c < 4; ++c) {
    if (c) __syncthreads();
    #pragma unroll
    for (int j = 0; j < 10; ++j) {
      int v = tid + j * 256;
      int e = v >> 6, kq = v & 63;
      ws4[v] = w4[e * 256 + c * 64 + kq];
    }
    float4 xv = x4[(size_t)token * 256 + c * 64 + lane];
    ushort4 s;
    s.x = f2bf(xv.x); s.y = f2bf(xv.y); s.z = f2bf(xv.z); s.w = f2bf(xv.w);
    reinterpret_cast<ushort4*>(xb + (size_t)token * HH)[c * 64 + lane] = s;
    __syncthreads();
    #pragma unroll
    for (int e = 0; e < E_T; ++e) {
      float4 w = ws4[e * 64 + lane];
      acc[e] += xv.x * w.x + xv.y * w.y + xv.z * w.z + xv.w * w.w;
    }
  }

  float mine = 0.f;
  #pragma unroll
  for (int e = 0; e < E_T; ++e) {
    float r = acc[e];
    #pragma unroll
    for (int o = 32; o; o >>= 1) r += __shfl_xor(r, o);
    if (lane == e) mine = r;
  }
  if (lane < E_T) logits[(size_t)token * E_T + lane] = mine;
}

// ---------------- kernel 2b: softmax + top-k, one thread per token ----------------
__global__ void k_topk(const float* __restrict__ logits, const float* __restrict__ bias,
                       float* __restrict__ zero_w, int* __restrict__ counts,
                       int* __restrict__ tok_list,
                       int* __restrict__ route_ep, float* __restrict__ route_w,
                       int* __restrict__ route_n) {
  int t = blockIdx.x * 64 + threadIdx.x;
  float l[E_T];
  const float4* lp = reinterpret_cast<const float4*>(logits + (size_t)t * E_T);
  #pragma unroll
  for (int j = 0; j < E_T / 4; ++j) {
    float4 v = lp[j];
    l[j * 4 + 0] = v.x; l[j * 4 + 1] = v.y; l[j * 4 + 2] = v.z; l[j * 4 + 3] = v.w;
  }
  float m = -FLT_MAX;
  #pragma unroll
  for (int e = 0; e < E_T; ++e) m = fmaxf(m, l[e]);
  float den = 0.f;
  #pragma unroll
  for (int e = 0; e < E_T; ++e) { l[e] = __expf(l[e] - m); den += l[e]; }
  float inv = 1.f / den;
  float sel[E_T];
  #pragma unroll
  for (int e = 0; e < E_T; ++e) { l[e] *= inv; sel[e] = l[e] + bias[e]; }

  unsigned long long used = 0ull;
  float zw = 0.f;
  int nr = 0;
  for (int k = 0; k < TOPK; ++k) {
    float bv = -FLT_MAX; int bj = 0;
    #pragma unroll
    for (int e = 0; e < E_T; ++e) {
      float v = ((used >> e) & 1ull) ? -FLT_MAX : sel[e];
      if (v > bv) { bv = v; bj = e; }
    }
    used |= 1ull << bj;
    float wgt = (bv - bias[bj]) * SCALE_F;
    if (bj >= E_R) {
      zw += wgt;
    } else {
      int p = atomicAdd(&counts[bj], 1);
      tok_list[bj * TT + p] = t;
      route_ep[t * TOPK + nr] = (bj << 16) | p;
      route_w[t * TOPK + nr] = wgt;
      nr++;
    }
  }
  zero_w[t] = zw;
  route_n[t] = nr;
}

// ---------------- kernel 3: prefix scan + compact tile list ----------------
__global__ void k_scan(const int* __restrict__ counts, int* __restrict__ offsets,
                       int* __restrict__ tiles) {
  if (threadIdx.x == 0) {
    int s = 0, idx = 0;
    for (int e = 0; e < E_R; ++e) {
      offsets[e] = s;
      int c = counts[e];
      s += c;
      for (int r0 = 0; r0 < c; r0 += 128) tiles[1 + idx++] = (e << 16) | r0;
    }
    offsets[E_R] = s;
    tiles[0] = idx;
  }
}

// ---------------- kernel 5: grouped GEMM1 + SiLU*up -> inter (bf16) ----------------
// 256 thr / 4 waves (2x2), block = 128 rows x (64 gate + 64 up), wave 64x(32g+32u).
// All-bf16, all-DMA staging with double-buffered LDS pipeline:
//   STAGE(t+1 -> other buf) issued BEFORE compute(t); __syncthreads per step drains
//   DMA(t+1) after a full compute phase has hidden its latency. 64.5KB -> 2 blocks/CU.
__global__ __launch_bounds__(256, 3) void k_gemm1(
    const unsigned short* __restrict__ xb, const unsigned short* __restrict__ gupb,
    const int* __restrict__ tok_list, const int* __restrict__ counts,
    const int* __restrict__ offsets, const int* __restrict__ tiles,
    unsigned short* __restrict__ inter) {
  const int nt = tiles[0];
  if ((int)blockIdx.y >= nt) return;
  const int tv = tiles[1 + blockIdx.y];
  const int e = tv >> 16;
  const int row0 = tv & 0xffff;
  const int cnt = counts[e];
  const int off = offsets[e];
  const int n0 = blockIdx.x * 64;
  const int tid = threadIdx.x;
  const int lane = tid & 63;
  const int wave = tid >> 6;       // 0..3
  const int wr = wave >> 1;        // 0..1 row half
  const int wc = wave & 1;         // 0..1 col half (32 of 64)

  __shared__ __align__(16) unsigned short lA[2][128 * 64];   // 16 KB x2
  __shared__ __align__(16) unsigned short lBg[2][64 * 64];   // 8 KB x2
  __shared__ __align__(16) unsigned short lBu[2][64 * 64];   // 8 KB x2
  __shared__ int toks[128];

  if (tid < 128) {
    int r = row0 + tid;
    toks[tid] = tok_list[e * TT + (r < cnt ? r : cnt - 1)];
  }
  __syncthreads();

  // A: 4 DMA/wave (8 rows each), pre-swizzled source chunk (row&7)
  unsigned aoff[4];
  #pragma unroll
  for (int i = 0; i < 4; ++i) {
    int lrow = wave * 32 + i * 8 + (lane >> 3);
    aoff[i] = (unsigned)toks[lrow] * HH + (((lane & 7) ^ (lrow & 7)) * 8);
  }
  // B (bf16 weights): 2 DMA/wave per matrix (8 rows each)
  const unsigned short* gb = gupb + (size_t)e * (1024 * HH);
  unsigned boff[2];
  #pragma unroll
  for (int i = 0; i < 2; ++i) {
    int lrow = wave * 16 + i * 8 + (lane >> 3);
    boff[i] = (unsigned)(n0 + lrow) * HH + (((lane & 7) ^ (lrow & 7)) * 8);
  }
  const unsigned upjump = 512u * HH;

  f32x4 accg[4][2] = {}; f32x4 accu[4][2] = {};

#define G1_STAGE(T, B)                                                          \
  {                                                                             \
    int k0s = (T) * 64;                                                         \
    _Pragma("unroll")                                                           \
    for (int i = 0; i < 4; ++i)                                                 \
      gload_lds16(xb + aoff[i] + k0s, lA[B] + (wave * 32 + i * 8) * 64);        \
    _Pragma("unroll")                                                           \
    for (int i = 0; i < 2; ++i) {                                               \
      gload_lds16(gb + boff[i] + k0s,          lBg[B] + (wave * 16 + i * 8) * 64); \
      gload_lds16(gb + boff[i] + upjump + k0s, lBu[B] + (wave * 16 + i * 8) * 64); \
    }                                                                           \
  }

  G1_STAGE(0, 0);
  __syncthreads();

  for (int t = 0; t < 16; ++t) {
    if (t < 15) {
      if ((t + 1) & 1) { G1_STAGE(t + 1, 1); } else { G1_STAGE(t + 1, 0); }
    }
    const unsigned short* cA  = (t & 1) ? lA[1]  : lA[0];
    const unsigned short* cBg = (t & 1) ? lBg[1] : lBg[0];
    const unsigned short* cBu = (t & 1) ? lBu[1] : lBu[0];
    #pragma unroll
    for (int ks = 0; ks < 2; ++ks) {
      int kb = ks * 32 + ((lane >> 4) << 3);
      bf16x8 a[4], g[2], u[2];
      #pragma unroll
      for (int i = 0; i < 4; ++i) a[i] = lds_frag(cA, wr * 64 + i * 16 + (lane & 15), kb);
      #pragma unroll
      for (int j = 0; j < 2; ++j) {
        g[j] = lds_frag(cBg, wc * 32 + j * 16 + (lane & 15), kb);
        u[j] = lds_frag(cBu, wc * 32 + j * 16 + (lane & 15), kb);
      }
      #pragma unroll
      for (int i = 0; i < 4; ++i)
        #pragma unroll
        for (int j = 0; j < 2; ++j) {
          accg[i][j] = mfma16(a[i], g[j], accg[i][j]);
          accu[i][j] = mfma16(a[i], u[j], accu[i][j]);
        }
    }
    __syncthreads();
  }

  #pragma unroll
  for (int i = 0; i < 4; ++i)
    #pragma unroll
    for (int j = 0; j < 2; ++j)
      #pragma unroll
      for (int r = 0; r < 4; ++r) {
        int rloc = wr * 64 + i * 16 + ((lane >> 4) << 2) + r;
        int grow = row0 + rloc;
        if (grow < cnt) {
          int col = n0 + wc * 32 + j * 16 + (lane & 15);
          float gv = accg[i][j][r], uv = accu[i][j][r];
          float act = gv / (1.f + __expf(-gv)) * uv;
          inter[(size_t)(off + grow) * II + col] = f2bf(act);
        }
      }
}

// ---------------- kernel 6: grouped GEMM2 -> inter2 rows (bf16, no atomics) ----------------
// 256 thr / 4 waves (2x2), block 128x128, wave 64x64, acc 4x4. Same dbuf DMA pipeline.
__global__ __launch_bounds__(256, 3) void k_gemm2(
    const unsigned short* __restrict__ inter, const unsigned short* __restrict__ dwnb,
    const int* __restrict__ counts, const int* __restrict__ offsets,
    const int* __restrict__ tiles, unsigned short* __restrict__ inter2) {
  const int nt = tiles[0];
  if ((int)blockIdx.y >= nt) return;
  const int tv = tiles[1 + blockIdx.y];
  const int e = tv >> 16;
  const int row0 = tv & 0xffff;
  const int cnt = counts[e];
  const int off = offsets[e];
  const int h0 = blockIdx.x * 128;
  const int tid = threadIdx.x;
  const int lane = tid & 63;
  const int wave = tid >> 6;
  const int wr = wave >> 1;        // 0..1
  const int wc = wave & 1;         // 0..1

  __shared__ __align__(16) unsigned short lA[2][128 * 64];   // 16 KB x2
  __shared__ __align__(16) unsigned short lB[2][128 * 64];   // 16 KB x2

  unsigned aoff[4];
  #pragma unroll
  for (int i = 0; i < 4; ++i) {
    int lrow = wave * 32 + i * 8 + (lane >> 3);
    int rr = row0 + lrow; rr = rr < cnt ? rr : cnt - 1;
    aoff[i] = (unsigned)(off + rr) * II + (((lane & 7) ^ (lrow & 7)) * 8);
  }
  const unsigned short* db = dwnb + (size_t)e * (HH * II);
  unsigned boff[4];
  #pragma unroll
  for (int i = 0; i < 4; ++i) {
    int lrow = wave * 32 + i * 8 + (lane >> 3);
    boff[i] = (unsigned)(h0 + lrow) * II + (((lane & 7) ^ (lrow & 7)) * 8);
  }

  f32x4 acc[4][4] = {};

#define G2_STAGE(T, B)                                                          \
  {                                                                             \
    int k0s = (T) * 64;                                                         \
    _Pragma("unroll")                                                           \
    for (int i = 0; i < 4; ++i)                                                 \
      gload_lds16(inter + aoff[i] + k0s, lA[B] + (wave * 32 + i * 8) * 64);     \
    _Pragma("unroll")                                                           \
    for (int i = 0; i < 4; ++i)                                                 \
      gload_lds16(db + boff[i] + k0s, lB[B] + (wave * 32 + i * 8) * 64);        \
  }

  G2_STAGE(0, 0);
  __syncthreads();

  for (int t = 0; t < 8; ++t) {
    if (t < 7) {
      if ((t + 1) & 1) { G2_STAGE(t + 1, 1); } else { G2_STAGE(t + 1, 0); }
    }
    const unsigned short* cA = (t & 1) ? lA[1] : lA[0];
    const unsigned short* cB = (t & 1) ? lB[1] : lB[0];
    #pragma unroll
    for (int ks = 0; ks < 2; ++ks) {
      int kb = ks * 32 + ((lane >> 4) << 3);
      bf16x8 a[4], b[4];
      #pragma unroll
      for (int i = 0; i < 4; ++i) a[i] = lds_frag(cA, wr * 64 + i * 16 + (lane & 15), kb);
      #pragma unroll
      for (int j = 0; j < 4; ++j) b[j] = lds_frag(cB, wc * 64 + j * 16 + (lane & 15), kb);
      #pragma unroll
      for (int i = 0; i < 4; ++i)
        #pragma unroll
        for (int j = 0; j < 4; ++j)
          acc[i][j] = mfma16(a[i], b[j], acc[i][j]);
    }
    __syncthreads();
  }

  #pragma unroll
  for (int i = 0; i < 4; ++i)
    #pragma unroll
    for (int j = 0; j < 4; ++j)
      #pragma unroll
      for (int r = 0; r < 4; ++r) {
        int rloc = wr * 64 + i * 16 + ((lane >> 4) << 2) + r;
        int grow = row0 + rloc;
        if (grow < cnt) {
          int h = h0 + wc * 64 + j * 16 + (lane & 15);
          inter2[(size_t)(off + grow) * HH + h] = f2bf(acc[i][j][r]);
        }
      }
}

// ---------------- kernel 7: combine  out = zw*x + sum_k w_k * y_k ----------------
__global__ __launch_bounds__(256) void k_combine(
    const float* __restrict__ x, const float* __restrict__ zero_w,
    const int* __restrict__ offsets, const int* __restrict__ route_ep,
    const float* __restrict__ route_w, const int* __restrict__ route_n,
    const unsigned short* __restrict__ inter2, float* __restrict__ out) {
  const int t = blockIdx.x;
  const int tid = threadIdx.x;
  const float zw = zero_w[t];
  const int n = route_n[t];
  float4 o = reinterpret_cast<const float4*>(x)[t * 256 + tid];
  o.x *= zw; o.y *= zw; o.z *= zw; o.w *= zw;
  for (int i = 0; i < n; ++i) {
    int ep = route_ep[t * TOPK + i];
    int row = offsets[ep >> 16] + (ep & 0xffff);
    float w = route_w[t * TOPK + i];
    ushort4 v = reinterpret_cast<const ushort4*>(inter2 + (size_t)row * HH)[tid];
    o.x += w * __builtin_bit_cast(float, (unsigned)v.x << 16);
    o.y += w * __builtin_bit_cast(float, (unsigned)v.y << 16);
    o.z += w * __builtin_bit_cast(float, (unsigned)v.z << 16);
    o.w += w * __builtin_bit_cast(float, (unsigned)v.w << 16);
  }
  reinterpret_cast<float4*>(out)[t * 256 + tid] = o;
}

// ---------------- ws layout ----------------
// xb      : TT*HH bf16          =  8,388,608 B   @ 0
// zero_w  : TT f32              =     16,384 B   @ 8,388,608
// counts  : 32 i32              =        128 B   @ 8,404,992
// offsets : 33 i32 (pad 256)    =        256 B   @ 8,405,120
// tok_list: 32*TT i32           =    524,288 B   @ 8,405,376
// logits  : TT*E_T f32          =    655,360 B   @ 8,929,664
// tiles   : 1+MAXTILES i32      =      4,096 B   @ 9,585,024
// route_ep: TT*6 i32            =     98,304 B   @ 9,589,120
// route_w : TT*6 f32            =     98,304 B   @ 9,687,424
// route_n : TT i32              =     16,384 B   @ 9,785,728
// inter   : 24576*II bf16       = 25,165,824 B   @ 9,802,112
// inter2  : 24576*HH bf16       = 50,331,648 B   @ 34,967,936
// gupb    : NGUP bf16           = 67,108,864 B   @ 85,299,584
// dwnb    : NDWN bf16           = 33,554,432 B   @ 152,408,448
// total ~= 186 MB

extern "C" void kernel_launch(void* const* d_in, const int* in_sizes, int n_in,
                              void* d_out, int out_size, void* d_ws, size_t ws_size,
                              hipStream_t stream) {
  const float* x    = (const float*)d_in[0];
  const float* wcls = (const float*)d_in[1];
  const float* bias = (const float*)d_in[2];
  const float* gup  = (const float*)d_in[3];
  const float* dwn  = (const float*)d_in[4];
  float* out = (float*)d_out;

  char* w = (char*)d_ws;
  unsigned short* xb    = (unsigned short*)(w + 0);
  float* zero_w         = (float*)(w + 8388608);
  int* counts           = (int*)(w + 8404992);
  int* offsets          = (int*)(w + 8405120);
  int* tok_list         = (int*)(w + 8405376);
  float* logits         = (float*)(w + 8929664);
  int* tiles            = (int*)(w + 9585024);
  int* route_ep         = (int*)(w + 9589120);
  float* route_w        = (float*)(w + 9687424);
  int* route_n          = (int*)(w + 9785728);
  unsigned short* inter = (unsigned short*)(w + 9802112);
  unsigned short* inter2 = (unsigned short*)(w + 34967936);
  unsigned short* gupb  = (unsigned short*)(w + 85299584);
  unsigned short* dwnb  = (unsigned short*)(w + 152408448);

  hipMemsetAsync(counts, 0, E_R * sizeof(int), stream);
  k_convert_w<<<(NGUP + NDWN) / 8 / 256, 256, 0, stream>>>(gup, dwn, (uint4*)gupb);
  k_logits<<<1024, 256, 0, stream>>>(x, wcls, logits, xb);
  k_topk<<<64, 64, 0, stream>>>(logits, bias, zero_w, counts, tok_list,
                                route_ep, route_w, route_n);
  k_scan<<<1, 64, 0, stream>>>(counts, offsets, tiles);
  k_gemm1<<<dim3(8, MAXTILES), 256, 0, stream>>>(xb, gupb, tok_list, counts, offsets, tiles, inter);
  k_gemm2<<<dim3(8, MAXTILES), 256, 0, stream>>>(inter, dwnb, counts, offsets, tiles, inter2);
  k_combine<<<TT, 256, 0, stream>>>(x, zero_w, offsets, route_ep, route_w, route_n,
                                    inter2, out);
}

// Round 12
// 222.563 us; speedup vs baseline: 1.1814x; 1.1814x over previous
//
#include <hip/hip_runtime.h>
#include <float.h>
#include <math.h>

// Problem constants
#define TT 4096          // tokens = B*S
#define HH 1024          // hidden
#define II 512           // expert ffn hidden
#define E_R 32
#define E_T 40
#define TOPK 6
#define SCALE_F 2.5f
#define MAXTILES 224     // >= sum_e ceil(cnt_e/128); (24576+32*127)/128 = 223.75

typedef __bf16 bf16x8 __attribute__((ext_vector_type(8)));
typedef float f32x4 __attribute__((ext_vector_type(4)));

__device__ inline unsigned short f2bf(float f) {
  __bf16 h = (__bf16)f;
  return __builtin_bit_cast(unsigned short, h);
}

__device__ inline bf16x8 cvt8v(float4 a, float4 b) {
  bf16x8 v;
  v[0] = (__bf16)a.x; v[1] = (__bf16)a.y; v[2] = (__bf16)a.z; v[3] = (__bf16)a.w;
  v[4] = (__bf16)b.x; v[5] = (__bf16)b.y; v[6] = (__bf16)b.z; v[7] = (__bf16)b.w;
  return v;
}

// async global->LDS, 16B per lane, wave-uniform LDS base (linear dest)
__device__ inline void gload_lds16(const void* g, void* l) {
  __builtin_amdgcn_global_load_lds(
      (__attribute__((address_space(1))) void*)g,
      (__attribute__((address_space(3))) void*)l, 16, 0, 0);
}

// bf16 LDS tile: [rows][64 bf16], row stride 128B, XOR swizzle byte^=((row&7)<<4);
// staged via gload_lds with pre-swizzled SOURCE, read with same XOR.
__device__ inline bf16x8 lds_frag(const unsigned short* base, int row, int kb) {
  int byte = (row * 128 + kb * 2) ^ ((row & 7) << 4);
  uint4 v = *reinterpret_cast<const uint4*>(reinterpret_cast<const char*>(base) + byte);
  return __builtin_bit_cast(bf16x8, v);
}

// fp32 LDS tile: [rows][64 f32], row stride 256B, chunk (16B) swizzle c ^= (row&15);
// staged via gload_lds with pre-swizzled source chunk; read applies same XOR.
// Reads two 16B chunks (8 fp32 = one k-fragment) and converts to bf16x8 in regs.
__device__ inline bf16x8 lds_frag_f32(const float* base, int row, int kb) {
  int key = row & 15;
  int c0 = (kb >> 2) ^ key;
  int c1 = ((kb >> 2) + 1) ^ key;
  const char* p = reinterpret_cast<const char*>(base) + row * 256;
  float4 lo = *reinterpret_cast<const float4*>(p + c0 * 16);
  float4 hi = *reinterpret_cast<const float4*>(p + c1 * 16);
  return cvt8v(lo, hi);
}

__device__ inline f32x4 mfma16(bf16x8 a, bf16x8 b, f32x4 c) {
  return __builtin_amdgcn_mfma_f32_16x16x32_bf16(a, b, c, 0, 0, 0);
}

// ---------------- kernel 2a: router logits (fp32 GEMV) + fused x->bf16 convert ----------
// Also zeroes counts[] (block 0) so no hipMemsetAsync is needed in kernel_launch.
__global__ __launch_bounds__(256) void k_logits(const float* __restrict__ x,
                                                const float* __restrict__ wcls,
                                                float* __restrict__ logits,
                                                unsigned short* __restrict__ xb,
                                                int* __restrict__ counts) {
  __shared__ float4 ws4[E_T * 64];                 // 40 KB
  const int tid = threadIdx.x;
  const int lane = tid & 63;
  const int wave = tid >> 6;
  const int token = blockIdx.x * 4 + wave;
  if (blockIdx.x == 0 && tid < E_R) counts[tid] = 0;
  const float4* x4 = reinterpret_cast<const float4*>(x);
  const float4* w4 = reinterpret_cast<const float4*>(wcls);

  float acc[E_T];
  #pragma unroll
  for (int e = 0; e < E_T; ++e) acc[e] = 0.f;

  for (int c = 0; c < 4; ++c) {
    if (c) __syncthreads();
    #pragma unroll
    for (int j = 0; j < 10; ++j) {
      int v = tid + j * 256;
      int e = v >> 6, kq = v & 63;
      ws4[v] = w4[e * 256 + c * 64 + kq];
    }
    float4 xv = x4[(size_t)token * 256 + c * 64 + lane];
    ushort4 s;
    s.x = f2bf(xv.x); s.y = f2bf(xv.y); s.z = f2bf(xv.z); s.w = f2bf(xv.w);
    reinterpret_cast<ushort4*>(xb + (size_t)token * HH)[c * 64 + lane] = s;
    __syncthreads();
    #pragma unroll
    for (int e = 0; e < E_T; ++e) {
      float4 w = ws4[e * 64 + lane];
      acc[e] += xv.x * w.x + xv.y * w.y + xv.z * w.z + xv.w * w.w;
    }
  }

  float mine = 0.f;
  #pragma unroll
  for (int e = 0; e < E_T; ++e) {
    float r = acc[e];
    #pragma unroll
    for (int o = 32; o; o >>= 1) r += __shfl_xor(r, o);
    if (lane == e) mine = r;
  }
  if (lane < E_T) logits[(size_t)token * E_T + lane] = mine;
}

// ---------------- kernel 2b: softmax + top-k, one thread per token ----------------
__global__ void k_topk(const float* __restrict__ logits, const float* __restrict__ bias,
                       float* __restrict__ zero_w, int* __restrict__ counts,
                       int* __restrict__ tok_list,
                       int* __restrict__ route_ep, float* __restrict__ route_w,
                       int* __restrict__ route_n) {
  int t = blockIdx.x * 64 + threadIdx.x;
  float l[E_T];
  const float4* lp = reinterpret_cast<const float4*>(logits + (size_t)t * E_T);
  #pragma unroll
  for (int j = 0; j < E_T / 4; ++j) {
    float4 v = lp[j];
    l[j * 4 + 0] = v.x; l[j * 4 + 1] = v.y; l[j * 4 + 2] = v.z; l[j * 4 + 3] = v.w;
  }
  float m = -FLT_MAX;
  #pragma unroll
  for (int e = 0; e < E_T; ++e) m = fmaxf(m, l[e]);
  float den = 0.f;
  #pragma unroll
  for (int e = 0; e < E_T; ++e) { l[e] = __expf(l[e] - m); den += l[e]; }
  float inv = 1.f / den;
  float sel[E_T];
  #pragma unroll
  for (int e = 0; e < E_T; ++e) { l[e] *= inv; sel[e] = l[e] + bias[e]; }

  unsigned long long used = 0ull;
  float zw = 0.f;
  int nr = 0;
  for (int k = 0; k < TOPK; ++k) {
    float bv = -FLT_MAX; int bj = 0;
    #pragma unroll
    for (int e = 0; e < E_T; ++e) {
      float v = ((used >> e) & 1ull) ? -FLT_MAX : sel[e];
      if (v > bv) { bv = v; bj = e; }
    }
    used |= 1ull << bj;
    float wgt = (bv - bias[bj]) * SCALE_F;
    if (bj >= E_R) {
      zw += wgt;
    } else {
      int p = atomicAdd(&counts[bj], 1);
      tok_list[bj * TT + p] = t;
      route_ep[t * TOPK + nr] = (bj << 16) | p;
      route_w[t * TOPK + nr] = wgt;
      nr++;
    }
  }
  zero_w[t] = zw;
  route_n[t] = nr;
}

// ---------------- kernel 3: prefix scan + compact tile list ----------------
__global__ void k_scan(const int* __restrict__ counts, int* __restrict__ offsets,
                       int* __restrict__ tiles) {
  if (threadIdx.x == 0) {
    int s = 0, idx = 0;
    for (int e = 0; e < E_R; ++e) {
      offsets[e] = s;
      int c = counts[e];
      s += c;
      for (int r0 = 0; r0 < c; r0 += 128) tiles[1 + idx++] = (e << 16) | r0;
    }
    offsets[E_R] = s;
    tiles[0] = idx;
  }
}

// ---------------- kernel 5: grouped GEMM1 + SiLU*up -> inter (bf16) ----------------
// 256 thr / 4 waves (2x2), block = 128 rows x (64 gate + 64 up), wave 64x(32g+32u).
// ALL staging is global_load_lds DMA: A bf16 (swz row&7), B fp32 (chunk swz row&15).
// fp32->bf16 conversion happens in-register during compute (cvt_pk overlaps MFMA).
__global__ __launch_bounds__(256, 3) void k_gemm1(
    const unsigned short* __restrict__ xb, const float* __restrict__ gup,
    const int* __restrict__ tok_list, const int* __restrict__ counts,
    const int* __restrict__ offsets, const int* __restrict__ tiles,
    unsigned short* __restrict__ inter) {
  const int nt = tiles[0];
  if ((int)blockIdx.y >= nt) return;
  const int tv = tiles[1 + blockIdx.y];
  const int e = tv >> 16;
  const int row0 = tv & 0xffff;
  const int cnt = counts[e];
  const int off = offsets[e];
  const int n0 = blockIdx.x * 64;
  const int tid = threadIdx.x;
  const int lane = tid & 63;
  const int wave = tid >> 6;       // 0..3
  const int wr = wave >> 1;        // 0..1 row half
  const int wc = wave & 1;         // 0..1 col half (32 of 64)

  __shared__ __align__(16) unsigned short lA[128 * 64];   // 16 KB bf16
  __shared__ __align__(16) float lBg[64 * 64];            // 16 KB fp32
  __shared__ __align__(16) float lBu[64 * 64];            // 16 KB fp32
  __shared__ int toks[128];

  if (tid < 128) {
    int r = row0 + tid;
    toks[tid] = tok_list[e * TT + (r < cnt ? r : cnt - 1)];
  }
  __syncthreads();

  // A: 4 gload_lds per wave (8 rows each), pre-swizzled source (row&7 XOR on 16B chunks)
  unsigned aoff[4];
  #pragma unroll
  for (int i = 0; i < 4; ++i) {
    int lrow = wave * 32 + i * 8 + (lane >> 3);
    aoff[i] = (unsigned)toks[lrow] * HH + (((lane & 7) ^ (lrow & 7)) * 8);
  }
  // B: 4 gload_lds per wave per matrix (4 rows each), pre-swizzled fp32 chunk (row&15)
  const float* gbase = gup + (size_t)e * 1024 * HH;
  unsigned boff[4];
  #pragma unroll
  for (int i = 0; i < 4; ++i) {
    int rt = wave * 16 + i * 4 + (lane >> 4);          // tile row 0..63
    boff[i] = (unsigned)(n0 + rt) * HH + (((lane & 15) ^ (rt & 15)) * 4);
  }
  const unsigned upjump = 512u * HH;

  f32x4 accg[4][2] = {}; f32x4 accu[4][2] = {};

  for (int k0 = 0; k0 < HH; k0 += 64) {
    #pragma unroll
    for (int i = 0; i < 4; ++i)
      gload_lds16(xb + aoff[i] + k0, lA + (wave * 32 + i * 8) * 64);
    #pragma unroll
    for (int i = 0; i < 4; ++i) {
      gload_lds16(gbase + boff[i] + k0,          lBg + (wave * 16 + i * 4) * 64);
      gload_lds16(gbase + boff[i] + upjump + k0, lBu + (wave * 16 + i * 4) * 64);
    }
    __syncthreads();
    #pragma unroll
    for (int ks = 0; ks < 2; ++ks) {
      int kb = ks * 32 + ((lane >> 4) << 3);
      bf16x8 a[4], g[2], u[2];
      #pragma unroll
      for (int i = 0; i < 4; ++i) a[i] = lds_frag(lA, wr * 64 + i * 16 + (lane & 15), kb);
      #pragma unroll
      for (int j = 0; j < 2; ++j) {
        g[j] = lds_frag_f32(lBg, wc * 32 + j * 16 + (lane & 15), kb);
        u[j] = lds_frag_f32(lBu, wc * 32 + j * 16 + (lane & 15), kb);
      }
      #pragma unroll
      for (int i = 0; i < 4; ++i)
        #pragma unroll
        for (int j = 0; j < 2; ++j) {
          accg[i][j] = mfma16(a[i], g[j], accg[i][j]);
          accu[i][j] = mfma16(a[i], u[j], accu[i][j]);
        }
    }
    __syncthreads();
  }

  #pragma unroll
  for (int i = 0; i < 4; ++i)
    #pragma unroll
    for (int j = 0; j < 2; ++j)
      #pragma unroll
      for (int r = 0; r < 4; ++r) {
        int rloc = wr * 64 + i * 16 + ((lane >> 4) << 2) + r;
        int grow = row0 + rloc;
        if (grow < cnt) {
          int col = n0 + wc * 32 + j * 16 + (lane & 15);
          float gv = accg[i][j][r], uv = accu[i][j][r];
          float act = gv / (1.f + __expf(-gv)) * uv;
          inter[(size_t)(off + grow) * II + col] = f2bf(act);
        }
      }
}

// ---------------- kernel 6: grouped GEMM2 -> inter2 rows (bf16, no atomics) ----------------
// 256 thr / 4 waves (2x2), block 128x128, wave 64x64, acc 4x4. Same all-DMA staging.
__global__ __launch_bounds__(256, 3) void k_gemm2(
    const unsigned short* __restrict__ inter, const float* __restrict__ dwn,
    const int* __restrict__ counts, const int* __restrict__ offsets,
    const int* __restrict__ tiles, unsigned short* __restrict__ inter2) {
  const int nt = tiles[0];
  if ((int)blockIdx.y >= nt) return;
  const int tv = tiles[1 + blockIdx.y];
  const int e = tv >> 16;
  const int row0 = tv & 0xffff;
  const int cnt = counts[e];
  const int off = offsets[e];
  const int h0 = blockIdx.x * 128;
  const int tid = threadIdx.x;
  const int lane = tid & 63;
  const int wave = tid >> 6;
  const int wr = wave >> 1;        // 0..1
  const int wc = wave & 1;         // 0..1

  __shared__ __align__(16) unsigned short lA[128 * 64];   // 16 KB bf16
  __shared__ __align__(16) float lB[128 * 64];            // 32 KB fp32

  // A: inter bf16, pre-swizzled source
  unsigned aoff[4];
  #pragma unroll
  for (int i = 0; i < 4; ++i) {
    int lrow = wave * 32 + i * 8 + (lane >> 3);
    int rr = row0 + lrow; rr = rr < cnt ? rr : cnt - 1;
    aoff[i] = (unsigned)(off + rr) * II + (((lane & 7) ^ (lrow & 7)) * 8);
  }
  // B: dwn fp32, 8 gload_lds per wave (4 rows each), chunk swizzle (row&15)
  const float* dbase = dwn + (size_t)e * HH * II;
  unsigned boff[8];
  #pragma unroll
  for (int i = 0; i < 8; ++i) {
    int rt = wave * 32 + i * 4 + (lane >> 4);          // tile row 0..127
    boff[i] = (unsigned)(h0 + rt) * II + (((lane & 15) ^ (rt & 15)) * 4);
  }

  f32x4 acc[4][4] = {};

  for (int k0 = 0; k0 < II; k0 += 64) {
    #pragma unroll
    for (int i = 0; i < 4; ++i)
      gload_lds16(inter + aoff[i] + k0, lA + (wave * 32 + i * 8) * 64);
    #pragma unroll
    for (int i = 0; i < 8; ++i)
      gload_lds16(dbase + boff[i] + k0, lB + (wave * 32 + i * 4) * 64);
    __syncthreads();
    #pragma unroll
    for (int ks = 0; ks < 2; ++ks) {
      int kb = ks * 32 + ((lane >> 4) << 3);
      bf16x8 a[4], b[4];
      #pragma unroll
      for (int i = 0; i < 4; ++i) a[i] = lds_frag(lA, wr * 64 + i * 16 + (lane & 15), kb);
      #pragma unroll
      for (int j = 0; j < 4; ++j) b[j] = lds_frag_f32(lB, wc * 64 + j * 16 + (lane & 15), kb);
      #pragma unroll
      for (int i = 0; i < 4; ++i)
        #pragma unroll
        for (int j = 0; j < 4; ++j)
          acc[i][j] = mfma16(a[i], b[j], acc[i][j]);
    }
    __syncthreads();
  }

  #pragma unroll
  for (int i = 0; i < 4; ++i)
    #pragma unroll
    for (int j = 0; j < 4; ++j)
      #pragma unroll
      for (int r = 0; r < 4; ++r) {
        int rloc = wr * 64 + i * 16 + ((lane >> 4) << 2) + r;
        int grow = row0 + rloc;
        if (grow < cnt) {
          int h = h0 + wc * 64 + j * 16 + (lane & 15);
          inter2[(size_t)(off + grow) * HH + h] = f2bf(acc[i][j][r]);
        }
      }
}

// ---------------- kernel 7: combine  out = zw*x + sum_k w_k * y_k ----------------
__global__ __launch_bounds__(256) void k_combine(
    const float* __restrict__ x, const float* __restrict__ zero_w,
    const int* __restrict__ offsets, const int* __restrict__ route_ep,
    const float* __restrict__ route_w, const int* __restrict__ route_n,
    const unsigned short* __restrict__ inter2, float* __restrict__ out) {
  const int t = blockIdx.x;
  const int tid = threadIdx.x;
  const float zw = zero_w[t];
  const int n = route_n[t];
  float4 o = reinterpret_cast<const float4*>(x)[t * 256 + tid];
  o.x *= zw; o.y *= zw; o.z *= zw; o.w *= zw;
  for (int i = 0; i < n; ++i) {
    int ep = route_ep[t * TOPK + i];
    int row = offsets[ep >> 16] + (ep & 0xffff);
    float w = route_w[t * TOPK + i];
    ushort4 v = reinterpret_cast<const ushort4*>(inter2 + (size_t)row * HH)[tid];
    o.x += w * __builtin_bit_cast(float, (unsigned)v.x << 16);
    o.y += w * __builtin_bit_cast(float, (unsigned)v.y << 16);
    o.z += w * __builtin_bit_cast(float, (unsigned)v.z << 16);
    o.w += w * __builtin_bit_cast(float, (unsigned)v.w << 16);
  }
  reinterpret_cast<float4*>(out)[t * 256 + tid] = o;
}

// ---------------- ws layout ----------------
// xb      : TT*HH bf16          =  8,388,608 B   @ 0
// zero_w  : TT f32              =     16,384 B   @ 8,388,608
// counts  : 32 i32              =        128 B   @ 8,404,992
// offsets : 33 i32 (pad 256)    =        256 B   @ 8,405,120
// tok_list: 32*TT i32           =    524,288 B   @ 8,405,376
// logits  : TT*E_T f32          =    655,360 B   @ 8,929,664
// tiles   : 1+MAXTILES i32      =      4,096 B   @ 9,585,024
// route_ep: TT*6 i32            =     98,304 B   @ 9,589,120
// route_w : TT*6 f32            =     98,304 B   @ 9,687,424
// route_n : TT i32              =     16,384 B   @ 9,785,728
// inter   : 24576*II bf16       = 25,165,824 B   @ 9,802,112
// inter2  : 24576*HH bf16       = 50,331,648 B   @ 34,967,936
// total ~= 85.3 MB

extern "C" void kernel_launch(void* const* d_in, const int* in_sizes, int n_in,
                              void* d_out, int out_size, void* d_ws, size_t ws_size,
                              hipStream_t stream) {
  const float* x    = (const float*)d_in[0];
  const float* wcls = (const float*)d_in[1];
  const float* bias = (const float*)d_in[2];
  const float* gup  = (const float*)d_in[3];
  const float* dwn  = (const float*)d_in[4];
  float* out = (float*)d_out;

  char* w = (char*)d_ws;
  unsigned short* xb    = (unsigned short*)(w + 0);
  float* zero_w         = (float*)(w + 8388608);
  int* counts           = (int*)(w + 8404992);
  int* offsets          = (int*)(w + 8405120);
  int* tok_list         = (int*)(w + 8405376);
  float* logits         = (float*)(w + 8929664);
  int* tiles            = (int*)(w + 9585024);
  int* route_ep         = (int*)(w + 9589120);
  float* route_w        = (float*)(w + 9687424);
  int* route_n          = (int*)(w + 9785728);
  unsigned short* inter = (unsigned short*)(w + 9802112);
  unsigned short* inter2 = (unsigned short*)(w + 34967936);

  k_logits<<<1024, 256, 0, stream>>>(x, wcls, logits, xb, counts);
  k_topk<<<64, 64, 0, stream>>>(logits, bias, zero_w, counts, tok_list,
                                route_ep, route_w, route_n);
  k_scan<<<1, 64, 0, stream>>>(counts, offsets, tiles);
  k_gemm1<<<dim3(8, MAXTILES), 256, 0, stream>>>(xb, gup, tok_list, counts, offsets, tiles, inter);
  k_gemm2<<<dim3(8, MAXTILES), 256, 0, stream>>>(inter, dwn, counts, offsets, tiles, inter2);
  k_combine<<<TT, 256, 0, stream>>>(x, zero_w, offsets, route_ep, route_w, route_n,
                                    inter2, out);
}